// Round 15
// baseline (647.901 us; speedup 1.0000x reference)
//
#include <hip/hip_runtime.h>
#include <hip/hip_bf16.h>

#define NEDGE 800000
#define NNODE 100000
#define LATD  128
#define NHEAD 4
#define WPAD  136            // padded LDS stride (q_kernel / fallback only)
#define TILES (NEDGE / 16)   // 50000 exact
#define QTILES (NNODE / 16)  // 6250 exact
#define NB ((NNODE + 1023) / 1024)  // 98 scan blocks

typedef _Float16 half8 __attribute__((ext_vector_type(8)));
typedef float    f32x4 __attribute__((ext_vector_type(4)));

__device__ __forceinline__ half8 load_frag_f32(const float* __restrict__ p) {
    const f32x4 a = *reinterpret_cast<const f32x4*>(p);
    const f32x4 b = *reinterpret_cast<const f32x4*>(p + 4);
    half8 r;
    r[0] = (_Float16)a[0]; r[1] = (_Float16)a[1];
    r[2] = (_Float16)a[2]; r[3] = (_Float16)a[3];
    r[4] = (_Float16)b[0]; r[5] = (_Float16)b[1];
    r[6] = (_Float16)b[2]; r[7] = (_Float16)b[3];
    return r;
}

// ---------------- qAll = embeds @ Q, fp16, PERMUTED layout ----------------
// storage: qAll[n*128 + (col&15)*8 + (col>>4)]
__global__ __launch_bounds__(512, 2) void q_kernel(
    const float* __restrict__ embeds,
    const float* __restrict__ Qw,
    _Float16* __restrict__ qAll)
{
    extern __shared__ _Float16 lds[];
    _Float16* Qt = lds;  // Qt[c][d] = Q[d][c]
    const int t = threadIdx.x;
    for (int idx = t; idx < LATD * LATD; idx += 512) {
        const int d = idx >> 7, c = idx & 127;
        Qt[c * WPAD + d] = (_Float16)Qw[idx];
    }
    __syncthreads();

    const int lane = t & 63;
    const int c16  = lane & 15;
    const int g    = lane >> 4;
    const int wave = (blockIdx.x << 3) + (t >> 6);
    const int nw   = gridDim.x << 3;

    for (int tile = wave; tile < QTILES; tile += nw) {
        const int n0 = tile << 4;
        const float* xrow = embeds + (size_t)(n0 + c16) * LATD + g * 8;
        f32x4 accQ[8] = {};
        #pragma unroll
        for (int ks = 0; ks < 4; ++ks) {
            const half8 ax = load_frag_f32(xrow + ks * 32);
            const int ko = ks * 32 + g * 8;
            #pragma unroll
            for (int nt = 0; nt < 8; ++nt) {
                const half8 bq = *reinterpret_cast<const half8*>(Qt + (nt * 16 + c16) * WPAD + ko);
                accQ[nt] = __builtin_amdgcn_mfma_f32_16x16x32_f16(ax, bq, accQ[nt], 0, 0, 0);
            }
        }
        #pragma unroll
        for (int r = 0; r < 4; ++r) {
            half8 h;
            #pragma unroll
            for (int nt = 0; nt < 8; ++nt) h[nt] = (_Float16)accQ[nt][r];
            *reinterpret_cast<half8*>(qAll + (size_t)(n0 + g * 4 + r) * LATD + c16 * 8) = h;
        }
    }
}

// ---------------- CSR build ----------------
__global__ void hist_kernel(const int* __restrict__ rows, int* __restrict__ counts) {
    const int e = blockIdx.x * 256 + threadIdx.x;
    if (e < NEDGE) atomicAdd(&counts[rows[e]], 1);
}

__global__ __launch_bounds__(1024) void scan1_kernel(
    const int* __restrict__ counts, int* __restrict__ offsets, int* __restrict__ partials)
{
    __shared__ int wt[16];
    __shared__ int wp[16];
    const int b = blockIdx.x;
    const int i = b * 1024 + threadIdx.x;
    const int v = (i < NNODE) ? counts[i] : 0;
    const int lane = threadIdx.x & 63, wid = threadIdx.x >> 6;
    int incl = v;
    #pragma unroll
    for (int d = 1; d < 64; d <<= 1) {
        const int x = __shfl_up(incl, d);
        if (lane >= d) incl += x;
    }
    if (lane == 63) wt[wid] = incl;
    __syncthreads();
    if (threadIdx.x == 0) {
        int s = 0;
        for (int k = 0; k < 16; ++k) { wp[k] = s; s += wt[k]; }
        partials[b] = s;
    }
    __syncthreads();
    if (i < NNODE) offsets[i] = incl - v + wp[wid];
}

__global__ __launch_bounds__(1024) void scan2_kernel(
    int* __restrict__ offsets, int* __restrict__ cursor, const int* __restrict__ partials)
{
    __shared__ int sp[128];
    const int b = blockIdx.x;
    if (threadIdx.x < NB) sp[threadIdx.x] = partials[threadIdx.x];
    __syncthreads();
    int s = 0;
    for (int k = 0; k < b; ++k) s += sp[k];
    const int i = b * 1024 + threadIdx.x;
    if (i < NNODE) {
        const int val = offsets[i] + s;
        offsets[i] = val;
        cursor[i]  = val;
    }
    if (b == 0 && threadIdx.x == 0) offsets[NNODE] = NEDGE;
}

__global__ void scatter_kernel(const int* __restrict__ rows,
                               int* __restrict__ cursor,
                               int* __restrict__ edgeIdx,
                               int* __restrict__ rowsSorted) {
    const int e = blockIdx.x * 256 + threadIdx.x;
    if (e < NEDGE) {
        const int r = rows[e];
        const int p = atomicAdd(&cursor[r], 1);
        edgeIdx[p]    = e;
        rowsSorted[p] = r;
    }
}

// ------ fused single-pass: sorted-edge P-MFMA kernel at 16 waves/CU.
//        Kt+Vt UNPADDED (2 x 32 KB = 64 KB -> 2 blocks/CU) with XOR swizzle:
//        store [c][d ^ ((c&7)<<3)], read at ko ^ ((c16&7)<<3)  (row&7 == c16&7). ------
__global__ __launch_bounds__(512, 2) void fused_kernel(
    const int*      __restrict__ edgeIdx,
    const int*      __restrict__ rowsSorted,
    const float*    __restrict__ colEmb,
    const _Float16* __restrict__ qAll,
    const float*    __restrict__ Kw,
    const float*    __restrict__ Vw,
    float* __restrict__ outAcc,
    float* __restrict__ attNorm,
    int tilesPerWave)
{
    extern __shared__ _Float16 lds[];
    _Float16* Kt = lds;                  // swizzled [c][d]
    _Float16* Vt = lds + LATD * LATD;
    const int t = threadIdx.x;
    for (int idx = t; idx < LATD * LATD; idx += 512) {
        const int d = idx >> 7, c = idx & 127;
        const int sd = d ^ ((c & 7) << 3);
        Kt[c * LATD + sd] = (_Float16)Kw[idx];
        Vt[c * LATD + sd] = (_Float16)Vw[idx];
    }
    __syncthreads();

    const int lane = t & 63;
    const int c16  = lane & 15;
    const int g    = lane >> 4;
    const int swz  = (c16 & 7) << 3;     // per-lane constant read swizzle
    const int wave = blockIdx.x * 8 + (t >> 6);
    const int tile0 = wave * tilesPerWave;
    int tile1 = tile0 + tilesPerWave;
    if (tile1 > TILES) tile1 = TILES;
    if (tile0 >= tile1) return;

    // preload first tile's indices
    int eA      = edgeIdx[(tile0 << 4) + c16];
    int rid16   = rowsSorted[(tile0 << 4) + c16];
    int4 rB     = *reinterpret_cast<const int4*>(rowsSorted + (tile0 << 4) + g * 4);
    int prevRow = (g == 0) ? -1 : rowsSorted[(tile0 << 4) + 4 * g - 1];

    for (int tile = tile0; tile < tile1; ++tile) {
        // issue this tile's colEmb gather immediately (4 outstanding 16B loads)
        const float* yrow = colEmb + (size_t)eA * LATD + g * 8;
        half8 ay[4];
        #pragma unroll
        for (int ks = 0; ks < 4; ++ks) ay[ks] = load_frag_f32(yrow + ks * 32);

        // q fragments for this lane's 4 D-rows (L2/IC-resident qAll)
        half8 qv[4];
        qv[0] = *reinterpret_cast<const half8*>(qAll + (size_t)rB.x * LATD + c16 * 8);
        qv[1] = *reinterpret_cast<const half8*>(qAll + (size_t)rB.y * LATD + c16 * 8);
        qv[2] = *reinterpret_cast<const half8*>(qAll + (size_t)rB.z * LATD + c16 * 8);
        qv[3] = *reinterpret_cast<const half8*>(qAll + (size_t)rB.w * LATD + c16 * 8);

        // prefetch next tile's indices
        const bool hasNext = (tile + 1 < tile1);
        int eAn = 0, rid16n = 0, prevRowN = 0;
        int4 rBn = rB;
        if (hasNext) {
            const int i1 = (tile + 1) << 4;
            eAn      = edgeIdx[i1 + c16];
            rid16n   = rowsSorted[i1 + c16];
            rBn      = *reinterpret_cast<const int4*>(rowsSorted + i1 + g * 4);
            prevRowN = (g == 0) ? -1 : rowsSorted[i1 + 4 * g - 1];
        }

        // k matmul (swizzled LDS reads)
        f32x4 accK[8] = {};
        #pragma unroll
        for (int ks = 0; ks < 4; ++ks) {
            const int koS = (ks * 32 + g * 8) ^ swz;
            #pragma unroll
            for (int nt = 0; nt < 8; ++nt) {
                const half8 bk = *reinterpret_cast<const half8*>(Kt + (nt * 16 + c16) * LATD + koS);
                accK[nt] = __builtin_amdgcn_mfma_f32_16x16x32_f16(ay[ks], bk, accK[nt], 0, 0, 0);
            }
        }

        // att = exp(clip(q.k)); butterfly over the 16 c16 lanes
        f32x4 eh[4];
        #pragma unroll
        for (int h = 0; h < 4; ++h) {
            f32x4 p;
            #pragma unroll
            for (int r = 0; r < 4; ++r)
                p[r] = accK[2 * h][r]     * (float)qv[r][2 * h]
                     + accK[2 * h + 1][r] * (float)qv[r][2 * h + 1];
            #pragma unroll
            for (int m = 1; m < 16; m <<= 1) {
                f32x4 q;
                q[0] = __shfl_xor(p[0], m);
                q[1] = __shfl_xor(p[1], m);
                q[2] = __shfl_xor(p[2], m);
                q[3] = __shfl_xor(p[3], m);
                p += q;
            }
            #pragma unroll
            for (int r = 0; r < 4; ++r)
                eh[h][r] = expf(fminf(10.0f, fmaxf(-10.0f, p[r])));
        }

        // v matmul (ay reused, swizzled LDS reads)
        f32x4 accV[8] = {};
        #pragma unroll
        for (int ks = 0; ks < 4; ++ks) {
            const int koS = (ks * 32 + g * 8) ^ swz;
            #pragma unroll
            for (int nt = 0; nt < 8; ++nt) {
                const half8 bv = *reinterpret_cast<const half8*>(Vt + (nt * 16 + c16) * LATD + koS);
                accV[nt] = __builtin_amdgcn_mfma_f32_16x16x32_f16(ay[ks], bv, accV[nt], 0, 0, 0);
            }
        }

        // P-MFMA segment totals (k = 8g+r mapping, halves j>=4 zero); D in place
        half8 Pf = {};
        Pf[0] = (rB.x == rid16) ? (_Float16)1.f : (_Float16)0.f;
        Pf[1] = (rB.y == rid16) ? (_Float16)1.f : (_Float16)0.f;
        Pf[2] = (rB.z == rid16) ? (_Float16)1.f : (_Float16)0.f;
        Pf[3] = (rB.w == rid16) ? (_Float16)1.f : (_Float16)0.f;

        const f32x4 zero4 = {};
        #pragma unroll
        for (int nt = 0; nt < 8; ++nt) {
            const f32x4 w4 = accV[nt] * eh[nt >> 1] * 0.015625f;   // 2^-6 fp16 guard
            half8 Wf = {};
            Wf[0] = (_Float16)w4[0]; Wf[1] = (_Float16)w4[1];
            Wf[2] = (_Float16)w4[2]; Wf[3] = (_Float16)w4[3];
            accV[nt] = __builtin_amdgcn_mfma_f32_16x16x32_f16(Pf, Wf, zero4, 0, 0, 0);
        }
        const f32x4 sel = (c16 == 0) ? eh[0] : (c16 == 1) ? eh[1] : (c16 == 2) ? eh[2] : eh[3];
        half8 Df = {};
        if (c16 < NHEAD) {
            Df[0] = (_Float16)sel[0]; Df[1] = (_Float16)sel[1];
            Df[2] = (_Float16)sel[2]; Df[3] = (_Float16)sel[3];
        }
        const f32x4 Dden = __builtin_amdgcn_mfma_f32_16x16x32_f16(Pf, Df, zero4, 0, 0, 0);

        // flush only at segment-head rows (accV holds D)
        #pragma unroll
        for (int r = 0; r < 4; ++r) {
            const int cur = (r == 0) ? rB.x : (r == 1) ? rB.y : (r == 2) ? rB.z : rB.w;
            const int prv = (r == 0) ? prevRow : (r == 1) ? rB.x : (r == 2) ? rB.y : rB.z;
            if (cur != prv) {
                #pragma unroll
                for (int nt = 0; nt < 8; ++nt)
                    atomicAdd(outAcc + (size_t)cur * LATD + nt * 16 + c16, accV[nt][r] * 64.0f);
                if (c16 < NHEAD) atomicAdd(attNorm + cur * NHEAD + c16, Dden[r]);
            }
        }

        if (hasNext) { eA = eAn; rid16 = rid16n; rB = rBn; prevRow = prevRowN; }
    }
}

// out[n, j] /= (attNorm[n, j/32] + 1e-8)
__global__ void norm_kernel(float* __restrict__ out, const float* __restrict__ attNorm) {
    const int i = blockIdx.x * 256 + threadIdx.x;
    if (i >= NNODE * 32) return;
    const int n = i >> 5;
    const int h = (i & 31) >> 3;
    const float s = attNorm[n * NHEAD + h] + 1e-8f;
    f32x4* p = reinterpret_cast<f32x4*>(out) + i;
    f32x4 v = *p;
    v[0] /= s; v[1] /= s; v[2] /= s; v[3] /= s;
    *p = v;
}

// ================= fallback (round-1 scatter path, unsorted) =================
__global__ __launch_bounds__(512, 2) void edge_kernel(
    const int*   __restrict__ rows,
    const float* __restrict__ colEmb,
    const float* __restrict__ embeds,
    const float* __restrict__ Qw,
    const float* __restrict__ Kw,
    const float* __restrict__ Vw,
    float* __restrict__ outAcc,
    float* __restrict__ attNorm)
{
    extern __shared__ _Float16 lds[];
    _Float16* Qt = lds;
    _Float16* Kt = lds + LATD * WPAD;
    _Float16* Vt = lds + 2 * LATD * WPAD;
    const int t = threadIdx.x;
    for (int idx = t; idx < LATD * LATD; idx += 512) {
        const int d = idx >> 7, c = idx & 127;
        Qt[c * WPAD + d] = (_Float16)Qw[idx];
        Kt[c * WPAD + d] = (_Float16)Kw[idx];
        Vt[c * WPAD + d] = (_Float16)Vw[idx];
    }
    __syncthreads();
    const int lane = t & 63;
    const int c16  = lane & 15;
    const int g    = lane >> 4;
    const int wave = (blockIdx.x << 3) + (t >> 6);
    const int nw   = gridDim.x << 3;
    for (int tile = wave; tile < TILES; tile += nw) {
        const int e0 = tile << 4;
        const int eA = e0 + c16;
        const int rA = rows[eA];
        const float* xrow = embeds + (size_t)rA * LATD + g * 8;
        const float* yrow = colEmb + (size_t)eA * LATD + g * 8;
        half8 ay[4];
        f32x4 accQ[8] = {};
        f32x4 accK[8] = {};
        #pragma unroll
        for (int ks = 0; ks < 4; ++ks) {
            const int ko = ks * 32 + g * 8;
            const half8 ax = load_frag_f32(xrow + ks * 32);
            ay[ks] = load_frag_f32(yrow + ks * 32);
            #pragma unroll
            for (int nt = 0; nt < 8; ++nt) {
                const int rofs = (nt * 16 + c16) * WPAD + ko;
                const half8 bq = *reinterpret_cast<const half8*>(Qt + rofs);
                const half8 bk = *reinterpret_cast<const half8*>(Kt + rofs);
                accQ[nt] = __builtin_amdgcn_mfma_f32_16x16x32_f16(ax,     bq, accQ[nt], 0, 0, 0);
                accK[nt] = __builtin_amdgcn_mfma_f32_16x16x32_f16(ay[ks], bk, accK[nt], 0, 0, 0);
            }
        }
        f32x4 eh[4];
        #pragma unroll
        for (int h = 0; h < 4; ++h) {
            f32x4 p = accQ[2 * h] * accK[2 * h] + accQ[2 * h + 1] * accK[2 * h + 1];
            #pragma unroll
            for (int m = 1; m < 16; m <<= 1) {
                f32x4 q;
                q[0] = __shfl_xor(p[0], m);
                q[1] = __shfl_xor(p[1], m);
                q[2] = __shfl_xor(p[2], m);
                q[3] = __shfl_xor(p[3], m);
                p += q;
            }
            #pragma unroll
            for (int r = 0; r < 4; ++r)
                eh[h][r] = expf(fminf(10.0f, fmaxf(-10.0f, p[r])));
        }
        int rB[4];
        #pragma unroll
        for (int r = 0; r < 4; ++r) rB[r] = rows[e0 + g * 4 + r];
        if (c16 < NHEAD) {
            const f32x4 sel = (c16 == 0) ? eh[0] : (c16 == 1) ? eh[1] : (c16 == 2) ? eh[2] : eh[3];
            #pragma unroll
            for (int r = 0; r < 4; ++r)
                atomicAdd(attNorm + rB[r] * NHEAD + c16, sel[r]);
        }
        f32x4 accV[8] = {};
        #pragma unroll
        for (int ks = 0; ks < 4; ++ks) {
            const int ko = ks * 32 + g * 8;
            #pragma unroll
            for (int nt = 0; nt < 8; ++nt) {
                const half8 bv = *reinterpret_cast<const half8*>(Vt + (nt * 16 + c16) * WPAD + ko);
                accV[nt] = __builtin_amdgcn_mfma_f32_16x16x32_f16(ay[ks], bv, accV[nt], 0, 0, 0);
            }
        }
        #pragma unroll
        for (int nt = 0; nt < 8; ++nt) {
            const f32x4 w = accV[nt] * eh[nt >> 1];
            #pragma unroll
            for (int r = 0; r < 4; ++r)
                atomicAdd(outAcc + (size_t)rB[r] * LATD + nt * 16 + c16, w[r]);
        }
    }
}

extern "C" void kernel_launch(void* const* d_in, const int* in_sizes, int n_in,
                              void* d_out, int out_size, void* d_ws, size_t ws_size,
                              hipStream_t stream) {
    const int*   rows   = (const int*)d_in[0];
    const float* colEmb = (const float*)d_in[1];
    const float* embeds = (const float*)d_in[2];
    const float* Qw     = (const float*)d_in[3];
    const float* Kw     = (const float*)d_in[4];
    const float* Vw     = (const float*)d_in[5];
    float* out = (float*)d_out;

    // ws layout (256B-multiple chunks)
    const size_t qAllB = (size_t)NNODE * LATD * sizeof(_Float16);   // 25.6 MB
    const size_t cntB  = 400128;
    const size_t offB  = 402176;
    const size_t curB  = 400128;
    const size_t eidxB = (size_t)NEDGE * sizeof(int);               // 3.2 MB
    const size_t rsrtB = (size_t)NEDGE * sizeof(int);               // 3.2 MB
    const size_t partB = 512;
    const size_t attB  = (size_t)NNODE * NHEAD * sizeof(float);     // 1.6 MB
    const size_t needB = qAllB + cntB + offB + curB + eidxB + rsrtB + partB + attB;

    if (ws_size >= needB) {
        char* w = (char*)d_ws;
        _Float16* qAll    = (_Float16*)w; w += qAllB;
        int*   counts     = (int*)w;    w += cntB;
        int*   offsets    = (int*)w;    w += offB;
        int*   cursor     = (int*)w;    w += curB;
        int*   edgeIdx    = (int*)w;    w += eidxB;
        int*   rowsSorted = (int*)w;    w += rsrtB;
        int*   partials   = (int*)w;    w += partB;
        float* attNorm    = (float*)w;

        hipMemsetAsync(counts,  0, (size_t)NNODE * sizeof(int), stream);
        hipMemsetAsync(out,     0, (size_t)NNODE * LATD * sizeof(float), stream);
        hipMemsetAsync(attNorm, 0, (size_t)NNODE * NHEAD * sizeof(float), stream);

        const int ldsQ = LATD * WPAD * sizeof(_Float16);      // 34,816 B
        hipFuncSetAttribute((const void*)q_kernel,
                            hipFuncAttributeMaxDynamicSharedMemorySize, ldsQ);
        q_kernel<<<(QTILES + 7) / 8, 512, ldsQ, stream>>>(embeds, Qw, qAll);

        hist_kernel<<<(NEDGE + 255) / 256, 256, 0, stream>>>(rows, counts);
        scan1_kernel<<<NB, 1024, 0, stream>>>(counts, offsets, partials);
        scan2_kernel<<<NB, 1024, 0, stream>>>(offsets, cursor, partials);
        scatter_kernel<<<(NEDGE + 255) / 256, 256, 0, stream>>>(rows, cursor, edgeIdx, rowsSorted);

        // fused single-pass: 64 KB LDS (unpadded, XOR-swizzled) -> 2 blocks/CU
        const int ldsF = 2 * LATD * LATD * sizeof(_Float16);  // 65,536 B
        hipFuncSetAttribute((const void*)fused_kernel,
                            hipFuncAttributeMaxDynamicSharedMemorySize, ldsF);
        const int nWaves = 1024 * 8;                       // 8192 waves
        const int tpw = (TILES + nWaves - 1) / nWaves;     // 7
        fused_kernel<<<1024, 512, ldsF, stream>>>(
            edgeIdx, rowsSorted, colEmb, qAll, Kw, Vw, out, attNorm, tpw);

        const int nVec = NNODE * 32;
        norm_kernel<<<(nVec + 255) / 256, 256, 0, stream>>>(out, attNorm);
    } else {
        // fallback: round-1 scatter path
        float* attNorm = (float*)d_ws;
        const int ldsBytes = 3 * LATD * WPAD * sizeof(_Float16);  // 104448 B
        hipMemsetAsync(out,     0, (size_t)NNODE * LATD  * sizeof(float), stream);
        hipMemsetAsync(attNorm, 0, (size_t)NNODE * NHEAD * sizeof(float), stream);
        hipFuncSetAttribute((const void*)edge_kernel,
                            hipFuncAttributeMaxDynamicSharedMemorySize, ldsBytes);
        edge_kernel<<<512, 512, ldsBytes, stream>>>(rows, colEmb, embeds, Qw, Kw, Vw, out, attNorm);
        const int nVec = NNODE * 32;
        norm_kernel<<<(nVec + 255) / 256, 256, 0, stream>>>(out, attNorm);
    }
}

// Round 16
// 418.732 us; speedup vs baseline: 1.5473x; 1.5473x over previous
//
#include <hip/hip_runtime.h>
#include <hip/hip_bf16.h>

#define NEDGE 800000
#define NNODE 100000
#define LATD  128
#define NHEAD 4
#define WPAD  136            // padded LDS row length (halves): 272B stride
#define TILES (NEDGE / 16)   // 50000 exact
#define QTILES (NNODE / 16)  // 6250 exact
#define NB ((NNODE + 1023) / 1024)  // 98 scan blocks

typedef _Float16 half8 __attribute__((ext_vector_type(8)));
typedef _Float16 half4t __attribute__((ext_vector_type(4)));
typedef float    f32x4 __attribute__((ext_vector_type(4)));

__device__ __forceinline__ half8 load_frag_f32(const float* __restrict__ p) {
    const f32x4 a = *reinterpret_cast<const f32x4*>(p);
    const f32x4 b = *reinterpret_cast<const f32x4*>(p + 4);
    half8 r;
    r[0] = (_Float16)a[0]; r[1] = (_Float16)a[1];
    r[2] = (_Float16)a[2]; r[3] = (_Float16)a[3];
    r[4] = (_Float16)b[0]; r[5] = (_Float16)b[1];
    r[6] = (_Float16)b[2]; r[7] = (_Float16)b[3];
    return r;
}

// ---------------- qAll = embeds @ Q, fp16, PERMUTED layout ----------------
// storage: qAll[n*128 + (col&15)*8 + (col>>4)]
__global__ __launch_bounds__(512, 2) void q_kernel(
    const float* __restrict__ embeds,
    const float* __restrict__ Qw,
    _Float16* __restrict__ qAll)
{
    extern __shared__ _Float16 lds[];
    _Float16* Qt = lds;  // Qt[c][d] = Q[d][c]
    const int t = threadIdx.x;
    for (int idx = t; idx < LATD * LATD; idx += 512) {
        const int d = idx >> 7, c = idx & 127;
        Qt[c * WPAD + d] = (_Float16)Qw[idx];
    }
    __syncthreads();

    const int lane = t & 63;
    const int c16  = lane & 15;
    const int g    = lane >> 4;
    const int wave = (blockIdx.x << 3) + (t >> 6);
    const int nw   = gridDim.x << 3;

    for (int tile = wave; tile < QTILES; tile += nw) {
        const int n0 = tile << 4;
        const float* xrow = embeds + (size_t)(n0 + c16) * LATD + g * 8;
        f32x4 accQ[8] = {};
        #pragma unroll
        for (int ks = 0; ks < 4; ++ks) {
            const half8 ax = load_frag_f32(xrow + ks * 32);
            const int ko = ks * 32 + g * 8;
            #pragma unroll
            for (int nt = 0; nt < 8; ++nt) {
                const half8 bq = *reinterpret_cast<const half8*>(Qt + (nt * 16 + c16) * WPAD + ko);
                accQ[nt] = __builtin_amdgcn_mfma_f32_16x16x32_f16(ax, bq, accQ[nt], 0, 0, 0);
            }
        }
        #pragma unroll
        for (int r = 0; r < 4; ++r) {
            half8 h;
            #pragma unroll
            for (int nt = 0; nt < 8; ++nt) h[nt] = (_Float16)accQ[nt][r];
            *reinterpret_cast<half8*>(qAll + (size_t)(n0 + g * 4 + r) * LATD + c16 * 8) = h;
        }
    }
}

// ---------------- CSR build ----------------
__global__ void hist_kernel(const int* __restrict__ rows, int* __restrict__ counts) {
    const int e = blockIdx.x * 256 + threadIdx.x;
    if (e < NEDGE) atomicAdd(&counts[rows[e]], 1);
}

__global__ __launch_bounds__(1024) void scan1_kernel(
    const int* __restrict__ counts, int* __restrict__ offsets, int* __restrict__ partials)
{
    __shared__ int wt[16];
    __shared__ int wp[16];
    const int b = blockIdx.x;
    const int i = b * 1024 + threadIdx.x;
    const int v = (i < NNODE) ? counts[i] : 0;
    const int lane = threadIdx.x & 63, wid = threadIdx.x >> 6;
    int incl = v;
    #pragma unroll
    for (int d = 1; d < 64; d <<= 1) {
        const int x = __shfl_up(incl, d);
        if (lane >= d) incl += x;
    }
    if (lane == 63) wt[wid] = incl;
    __syncthreads();
    if (threadIdx.x == 0) {
        int s = 0;
        for (int k = 0; k < 16; ++k) { wp[k] = s; s += wt[k]; }
        partials[b] = s;
    }
    __syncthreads();
    if (i < NNODE) offsets[i] = incl - v + wp[wid];
}

__global__ __launch_bounds__(1024) void scan2_kernel(
    int* __restrict__ offsets, int* __restrict__ cursor, const int* __restrict__ partials)
{
    __shared__ int sp[128];
    const int b = blockIdx.x;
    if (threadIdx.x < NB) sp[threadIdx.x] = partials[threadIdx.x];
    __syncthreads();
    int s = 0;
    for (int k = 0; k < b; ++k) s += sp[k];
    const int i = b * 1024 + threadIdx.x;
    if (i < NNODE) {
        const int val = offsets[i] + s;
        offsets[i] = val;
        cursor[i]  = val;
    }
    if (b == 0 && threadIdx.x == 0) offsets[NNODE] = NEDGE;
}

__global__ void scatter_kernel(const int* __restrict__ rows,
                               int* __restrict__ cursor,
                               int* __restrict__ edgeIdx,
                               int* __restrict__ rowsSorted,
                               int* __restrict__ rank) {
    const int e = blockIdx.x * 256 + threadIdx.x;
    if (e < NEDGE) {
        const int r = rows[e];
        const int p = atomicAdd(&cursor[r], 1);
        edgeIdx[p]    = e;
        rowsSorted[p] = r;
        rank[e]       = p;
    }
}

// ------ phase 1: att_kernel. Natural-order streaming colEmb, Kt-ONLY LDS.
//        attN written at SORTED position rank[e] (L2-resident 6.4 MB). ------
__global__ __launch_bounds__(512, 2) void att_kernel(
    const int*      __restrict__ rows,
    const int*      __restrict__ rank,
    const float*    __restrict__ colEmb,
    const _Float16* __restrict__ qAll,
    const float*    __restrict__ Kw,
    _Float16* __restrict__ attN)
{
    extern __shared__ _Float16 lds[];
    _Float16* Kt = lds;                 // Kt[c][d] = K[d][c]
    const int t = threadIdx.x;
    for (int idx = t; idx < LATD * LATD; idx += 512) {
        const int d = idx >> 7, c = idx & 127;
        Kt[c * WPAD + d] = (_Float16)Kw[idx];
    }
    __syncthreads();

    const int lane = t & 63;
    const int c16  = lane & 15;
    const int g    = lane >> 4;
    const int wave = blockIdx.x * 8 + (t >> 6);
    const int nw   = gridDim.x * 8;

    for (int tile = wave; tile < TILES; tile += nw) {
        const int e0 = tile << 4;
        const float* yrow = colEmb + (size_t)(e0 + c16) * LATD + g * 8;  // streaming

        half8 ay[4];
        #pragma unroll
        for (int ks = 0; ks < 4; ++ks) ay[ks] = load_frag_f32(yrow + ks * 32);

        // q rows (gather from 25.6 MB L2/IC-resident qAll)
        const int4 rW = *reinterpret_cast<const int4*>(rows + e0 + g * 4);
        half8 qv[4];
        qv[0] = *reinterpret_cast<const half8*>(qAll + (size_t)rW.x * LATD + c16 * 8);
        qv[1] = *reinterpret_cast<const half8*>(qAll + (size_t)rW.y * LATD + c16 * 8);
        qv[2] = *reinterpret_cast<const half8*>(qAll + (size_t)rW.z * LATD + c16 * 8);
        qv[3] = *reinterpret_cast<const half8*>(qAll + (size_t)rW.w * LATD + c16 * 8);

        f32x4 accK[8] = {};
        #pragma unroll
        for (int ks = 0; ks < 4; ++ks) {
            const int ko = ks * 32 + g * 8;
            #pragma unroll
            for (int nt = 0; nt < 8; ++nt) {
                const half8 bk = *reinterpret_cast<const half8*>(Kt + (nt * 16 + c16) * WPAD + ko);
                accK[nt] = __builtin_amdgcn_mfma_f32_16x16x32_f16(ay[ks], bk, accK[nt], 0, 0, 0);
            }
        }

        // att = exp(clip(q.k)) per head; butterfly over the 16 c16 lanes
        f32x4 eh[4];
        #pragma unroll
        for (int h = 0; h < 4; ++h) {
            f32x4 p;
            #pragma unroll
            for (int r = 0; r < 4; ++r)
                p[r] = accK[2 * h][r]     * (float)qv[r][2 * h]
                     + accK[2 * h + 1][r] * (float)qv[r][2 * h + 1];
            #pragma unroll
            for (int m = 1; m < 16; m <<= 1) {
                f32x4 q;
                q[0] = __shfl_xor(p[0], m);
                q[1] = __shfl_xor(p[1], m);
                q[2] = __shfl_xor(p[2], m);
                q[3] = __shfl_xor(p[3], m);
                p += q;
            }
            #pragma unroll
            for (int r = 0; r < 4; ++r)
                eh[h][r] = expf(fminf(10.0f, fmaxf(-10.0f, p[r])));
        }

        // attN store at SORTED positions: lanes c16<4 write head c16 for their 4 rows
        const f32x4 sel = (c16 == 0) ? eh[0] : (c16 == 1) ? eh[1] : (c16 == 2) ? eh[2] : eh[3];
        if (c16 < NHEAD) {
            const int4 rk = *reinterpret_cast<const int4*>(rank + e0 + g * 4);
            attN[(size_t)rk.x * NHEAD + c16] = (_Float16)sel[0];
            attN[(size_t)rk.y * NHEAD + c16] = (_Float16)sel[1];
            attN[(size_t)rk.z * NHEAD + c16] = (_Float16)sel[2];
            attN[(size_t)rk.w * NHEAD + c16] = (_Float16)sel[3];
        }
    }
}

// ------ phase 2: pv_kernel (512,2). Sequential attN reads; head-mask ballots;
//        plain-store fast path for tile-complete nodes, atomics for spanning. ------
__global__ __launch_bounds__(512, 2) void pv_kernel(
    const int*      __restrict__ edgeIdx,
    const int*      __restrict__ rowsSorted,
    const float*    __restrict__ colEmb,
    const _Float16* __restrict__ attN,
    const float*    __restrict__ Vw,
    float* __restrict__ outAcc,
    float* __restrict__ attNorm,
    int tilesPerWave)
{
    extern __shared__ _Float16 lds[];
    _Float16* Vt = lds;                 // Vt[c][d] = V[d][c]
    const int t = threadIdx.x;
    for (int idx = t; idx < LATD * LATD; idx += 512) {
        const int d = idx >> 7, c = idx & 127;
        Vt[c * WPAD + d] = (_Float16)Vw[idx];
    }
    __syncthreads();

    const int lane = t & 63;
    const int c16  = lane & 15;
    const int g    = lane >> 4;
    const int wave = blockIdx.x * 8 + (t >> 6);
    const int tile0 = wave * tilesPerWave;
    int tile1 = tile0 + tilesPerWave;
    if (tile1 > TILES) tile1 = TILES;
    if (tile0 >= tile1) return;

    // preload first tile's indices
    int eA    = edgeIdx[(tile0 << 4) + c16];
    int rid16 = rowsSorted[(tile0 << 4) + c16];
    int4 rB   = *reinterpret_cast<const int4*>(rowsSorted + (tile0 << 4) + g * 4);

    for (int tile = tile0; tile < tile1; ++tile) {
        const int e0 = tile << 4;

        // issue this tile's colEmb gather immediately (4 outstanding 16B loads)
        const float* yrow = colEmb + (size_t)eA * LATD + g * 8;
        half8 ay[4];
        #pragma unroll
        for (int ks = 0; ks < 4; ++ks) ay[ks] = load_frag_f32(yrow + ks * 32);

        // sequential attN reads for this lane's 4 rows (L2-resident, broadcast)
        half4t a4[4];
        a4[0] = *reinterpret_cast<const half4t*>(attN + (size_t)(e0 + 4 * g + 0) * NHEAD);
        a4[1] = *reinterpret_cast<const half4t*>(attN + (size_t)(e0 + 4 * g + 1) * NHEAD);
        a4[2] = *reinterpret_cast<const half4t*>(attN + (size_t)(e0 + 4 * g + 2) * NHEAD);
        a4[3] = *reinterpret_cast<const half4t*>(attN + (size_t)(e0 + 4 * g + 3) * NHEAD);

        // global prev row (node of row 4g-1) and row after this tile
        const int pPrev  = (e0 + 4 * g == 0) ? -1 : rowsSorted[e0 + 4 * g - 1];
        const int nextRow = (e0 + 16 < NEDGE) ? rowsSorted[e0 + 16] : -1;

        // prefetch next tile's indices
        const bool hasNext = (tile + 1 < tile1);
        int eAn = 0, rid16n = 0;
        int4 rBn = rB;
        if (hasNext) {
            const int i1 = (tile + 1) << 4;
            eAn    = edgeIdx[i1 + c16];
            rid16n = rowsSorted[i1 + c16];
            rBn    = *reinterpret_cast<const int4*>(rowsSorted + i1 + g * 4);
        }

        // v matmul
        f32x4 accV[8] = {};
        #pragma unroll
        for (int ks = 0; ks < 4; ++ks) {
            const int ko = ks * 32 + g * 8;
            #pragma unroll
            for (int nt = 0; nt < 8; ++nt) {
                const half8 bv = *reinterpret_cast<const half8*>(Vt + (nt * 16 + c16) * WPAD + ko);
                accV[nt] = __builtin_amdgcn_mfma_f32_16x16x32_f16(ay[ks], bv, accV[nt], 0, 0, 0);
            }
        }

        // head flags for this lane's 4 rows (true heads, global prev)
        const bool h0 = (rB.x != pPrev);
        const bool h1 = (rB.y != rB.x);
        const bool h2 = (rB.z != rB.y);
        const bool h3 = (rB.w != rB.z);
        const unsigned long long m0 = __ballot(h0);
        const unsigned long long m1 = __ballot(h1);
        const unsigned long long m2 = __ballot(h2);
        const unsigned long long m3 = __ballot(h3);
        unsigned hm = 0;
        #pragma unroll
        for (int gg = 0; gg < 4; ++gg) {
            hm |= (unsigned)((m0 >> (gg * 16)) & 1ULL) << (4 * gg + 0);
            hm |= (unsigned)((m1 >> (gg * 16)) & 1ULL) << (4 * gg + 1);
            hm |= (unsigned)((m2 >> (gg * 16)) & 1ULL) << (4 * gg + 2);
            hm |= (unsigned)((m3 >> (gg * 16)) & 1ULL) << (4 * gg + 3);
        }

        // P-MFMA segment totals (k = 8g+r mapping, halves j>=4 zero); D in place
        half8 Pf = {};
        Pf[0] = (rB.x == rid16) ? (_Float16)1.f : (_Float16)0.f;
        Pf[1] = (rB.y == rid16) ? (_Float16)1.f : (_Float16)0.f;
        Pf[2] = (rB.z == rid16) ? (_Float16)1.f : (_Float16)0.f;
        Pf[3] = (rB.w == rid16) ? (_Float16)1.f : (_Float16)0.f;

        const f32x4 zero4 = {};
        #pragma unroll
        for (int nt = 0; nt < 8; ++nt) {
            const int h = nt >> 1;
            half8 Wf = {};
            Wf[0] = (_Float16)(accV[nt][0] * (float)a4[0][h] * 0.015625f);
            Wf[1] = (_Float16)(accV[nt][1] * (float)a4[1][h] * 0.015625f);
            Wf[2] = (_Float16)(accV[nt][2] * (float)a4[2][h] * 0.015625f);
            Wf[3] = (_Float16)(accV[nt][3] * (float)a4[3][h] * 0.015625f);
            accV[nt] = __builtin_amdgcn_mfma_f32_16x16x32_f16(Pf, Wf, zero4, 0, 0, 0);
        }
        half8 Df = {};
        if (c16 < NHEAD) {
            Df[0] = a4[0][c16]; Df[1] = a4[1][c16];
            Df[2] = a4[2][c16]; Df[3] = a4[3][c16];
        }
        const f32x4 Dden = __builtin_amdgcn_mfma_f32_16x16x32_f16(Pf, Df, zero4, 0, 0, 0);

        // flush: plain store for tile-complete nodes, atomic for spanning/partial
        #pragma unroll
        for (int r = 0; r < 4; ++r) {
            const int i = 4 * g + r;
            const int cur = (r == 0) ? rB.x : (r == 1) ? rB.y : (r == 2) ? rB.z : rB.w;
            const bool isHead = (hm >> i) & 1;
            if (isHead || i == 0) {
                const bool complete = isHead && (((hm >> (i + 1)) != 0) || (nextRow != cur));
                if (complete) {
                    #pragma unroll
                    for (int nt = 0; nt < 8; ++nt)
                        outAcc[(size_t)cur * LATD + nt * 16 + c16] = accV[nt][r] * 64.0f;
                    if (c16 < NHEAD) attNorm[cur * NHEAD + c16] = Dden[r];
                } else {
                    #pragma unroll
                    for (int nt = 0; nt < 8; ++nt)
                        atomicAdd(outAcc + (size_t)cur * LATD + nt * 16 + c16, accV[nt][r] * 64.0f);
                    if (c16 < NHEAD) atomicAdd(attNorm + cur * NHEAD + c16, Dden[r]);
                }
            }
        }

        if (hasNext) { eA = eAn; rid16 = rid16n; rB = rBn; }
    }
}

// out[n, j] /= (attNorm[n, j/32] + 1e-8)
__global__ void norm_kernel(float* __restrict__ out, const float* __restrict__ attNorm) {
    const int i = blockIdx.x * 256 + threadIdx.x;
    if (i >= NNODE * 32) return;
    const int n = i >> 5;
    const int h = (i & 31) >> 3;
    const float s = attNorm[n * NHEAD + h] + 1e-8f;
    f32x4* p = reinterpret_cast<f32x4*>(out) + i;
    f32x4 v = *p;
    v[0] /= s; v[1] /= s; v[2] /= s; v[3] /= s;
    *p = v;
}

// ================= fallback (round-1 scatter path, unsorted) =================
__global__ __launch_bounds__(512, 2) void edge_kernel(
    const int*   __restrict__ rows,
    const float* __restrict__ colEmb,
    const float* __restrict__ embeds,
    const float* __restrict__ Qw,
    const float* __restrict__ Kw,
    const float* __restrict__ Vw,
    float* __restrict__ outAcc,
    float* __restrict__ attNorm)
{
    extern __shared__ _Float16 lds[];
    _Float16* Qt = lds;
    _Float16* Kt = lds + LATD * WPAD;
    _Float16* Vt = lds + 2 * LATD * WPAD;
    const int t = threadIdx.x;
    for (int idx = t; idx < LATD * LATD; idx += 512) {
        const int d = idx >> 7, c = idx & 127;
        Qt[c * WPAD + d] = (_Float16)Qw[idx];
        Kt[c * WPAD + d] = (_Float16)Kw[idx];
        Vt[c * WPAD + d] = (_Float16)Vw[idx];
    }
    __syncthreads();
    const int lane = t & 63;
    const int c16  = lane & 15;
    const int g    = lane >> 4;
    const int wave = (blockIdx.x << 3) + (t >> 6);
    const int nw   = gridDim.x << 3;
    for (int tile = wave; tile < TILES; tile += nw) {
        const int e0 = tile << 4;
        const int eA = e0 + c16;
        const int rA = rows[eA];
        const float* xrow = embeds + (size_t)rA * LATD + g * 8;
        const float* yrow = colEmb + (size_t)eA * LATD + g * 8;
        half8 ay[4];
        f32x4 accQ[8] = {};
        f32x4 accK[8] = {};
        #pragma unroll
        for (int ks = 0; ks < 4; ++ks) {
            const int ko = ks * 32 + g * 8;
            const half8 ax = load_frag_f32(xrow + ks * 32);
            ay[ks] = load_frag_f32(yrow + ks * 32);
            #pragma unroll
            for (int nt = 0; nt < 8; ++nt) {
                const int rofs = (nt * 16 + c16) * WPAD + ko;
                const half8 bq = *reinterpret_cast<const half8*>(Qt + rofs);
                const half8 bk = *reinterpret_cast<const half8*>(Kt + rofs);
                accQ[nt] = __builtin_amdgcn_mfma_f32_16x16x32_f16(ax,     bq, accQ[nt], 0, 0, 0);
                accK[nt] = __builtin_amdgcn_mfma_f32_16x16x32_f16(ay[ks], bk, accK[nt], 0, 0, 0);
            }
        }
        f32x4 eh[4];
        #pragma unroll
        for (int h = 0; h < 4; ++h) {
            f32x4 p = accQ[2 * h] * accK[2 * h] + accQ[2 * h + 1] * accK[2 * h + 1];
            #pragma unroll
            for (int m = 1; m < 16; m <<= 1) {
                f32x4 q;
                q[0] = __shfl_xor(p[0], m);
                q[1] = __shfl_xor(p[1], m);
                q[2] = __shfl_xor(p[2], m);
                q[3] = __shfl_xor(p[3], m);
                p += q;
            }
            #pragma unroll
            for (int r = 0; r < 4; ++r)
                eh[h][r] = expf(fminf(10.0f, fmaxf(-10.0f, p[r])));
        }
        int rB[4];
        #pragma unroll
        for (int r = 0; r < 4; ++r) rB[r] = rows[e0 + g * 4 + r];
        if (c16 < NHEAD) {
            const f32x4 sel = (c16 == 0) ? eh[0] : (c16 == 1) ? eh[1] : (c16 == 2) ? eh[2] : eh[3];
            #pragma unroll
            for (int r = 0; r < 4; ++r)
                atomicAdd(attNorm + rB[r] * NHEAD + c16, sel[r]);
        }
        f32x4 accV[8] = {};
        #pragma unroll
        for (int ks = 0; ks < 4; ++ks) {
            const int ko = ks * 32 + g * 8;
            #pragma unroll
            for (int nt = 0; nt < 8; ++nt) {
                const half8 bv = *reinterpret_cast<const half8*>(Vt + (nt * 16 + c16) * WPAD + ko);
                accV[nt] = __builtin_amdgcn_mfma_f32_16x16x32_f16(ay[ks], bv, accV[nt], 0, 0, 0);
            }
        }
        #pragma unroll
        for (int nt = 0; nt < 8; ++nt) {
            const f32x4 w = accV[nt] * eh[nt >> 1];
            #pragma unroll
            for (int r = 0; r < 4; ++r)
                atomicAdd(outAcc + (size_t)rB[r] * LATD + nt * 16 + c16, w[r]);
        }
    }
}

extern "C" void kernel_launch(void* const* d_in, const int* in_sizes, int n_in,
                              void* d_out, int out_size, void* d_ws, size_t ws_size,
                              hipStream_t stream) {
    const int*   rows   = (const int*)d_in[0];
    const float* colEmb = (const float*)d_in[1];
    const float* embeds = (const float*)d_in[2];
    const float* Qw     = (const float*)d_in[3];
    const float* Kw     = (const float*)d_in[4];
    const float* Vw     = (const float*)d_in[5];
    float* out = (float*)d_out;

    // ws layout (256B-multiple chunks)
    const size_t qAllB = (size_t)NNODE * LATD * sizeof(_Float16);   // 25.6 MB
    const size_t cntB  = 400128;
    const size_t offB  = 402176;
    const size_t curB  = 400128;
    const size_t eidxB = (size_t)NEDGE * sizeof(int);               // 3.2 MB
    const size_t rsrtB = (size_t)NEDGE * sizeof(int);               // 3.2 MB
    const size_t rnkB  = (size_t)NEDGE * sizeof(int);               // 3.2 MB
    const size_t partB = 512;
    const size_t attNB = (size_t)NEDGE * NHEAD * sizeof(_Float16);  // 6.4 MB
    const size_t attB  = (size_t)NNODE * NHEAD * sizeof(float);     // 1.6 MB
    const size_t needB = qAllB + cntB + offB + curB + eidxB + rsrtB + rnkB + partB + attNB + attB;

    if (ws_size >= needB) {
        char* w = (char*)d_ws;
        _Float16* qAll    = (_Float16*)w; w += qAllB;
        int*   counts     = (int*)w;    w += cntB;
        int*   offsets    = (int*)w;    w += offB;
        int*   cursor     = (int*)w;    w += curB;
        int*   edgeIdx    = (int*)w;    w += eidxB;
        int*   rowsSorted = (int*)w;    w += rsrtB;
        int*   rank       = (int*)w;    w += rnkB;
        int*   partials   = (int*)w;    w += partB;
        _Float16* attN    = (_Float16*)w; w += attNB;
        float* attNorm    = (float*)w;

        hipMemsetAsync(counts,  0, (size_t)NNODE * sizeof(int), stream);
        hipMemsetAsync(out,     0, (size_t)NNODE * LATD * sizeof(float), stream);
        hipMemsetAsync(attNorm, 0, (size_t)NNODE * NHEAD * sizeof(float), stream);

        const int ldsQ = LATD * WPAD * sizeof(_Float16);      // 34,816 B
        hipFuncSetAttribute((const void*)q_kernel,
                            hipFuncAttributeMaxDynamicSharedMemorySize, ldsQ);
        q_kernel<<<(QTILES + 7) / 8, 512, ldsQ, stream>>>(embeds, Qw, qAll);

        hist_kernel<<<(NEDGE + 255) / 256, 256, 0, stream>>>(rows, counts);
        scan1_kernel<<<NB, 1024, 0, stream>>>(counts, offsets, partials);
        scan2_kernel<<<NB, 1024, 0, stream>>>(offsets, cursor, partials);
        scatter_kernel<<<(NEDGE + 255) / 256, 256, 0, stream>>>(rows, cursor, edgeIdx, rowsSorted, rank);

        // phase 1: att (Kt-only LDS, attN scattered to sorted positions)
        hipFuncSetAttribute((const void*)att_kernel,
                            hipFuncAttributeMaxDynamicSharedMemorySize, ldsQ);
        att_kernel<<<1024, 512, ldsQ, stream>>>(rows, rank, colEmb, qAll, Kw, attN);

        // phase 2: pv (Vt-only LDS), plain-store fast path + atomics for spanning
        hipFuncSetAttribute((const void*)pv_kernel,
                            hipFuncAttributeMaxDynamicSharedMemorySize, ldsQ);
        const int nWaves = 1024 * 8;                       // 8192 waves
        const int tpw = (TILES + nWaves - 1) / nWaves;     // 7
        pv_kernel<<<1024, 512, ldsQ, stream>>>(
            edgeIdx, rowsSorted, colEmb, attN, Vw, out, attNorm, tpw);

        const int nVec = NNODE * 32;
        norm_kernel<<<(nVec + 255) / 256, 256, 0, stream>>>(out, attNorm);
    } else {
        // fallback: round-1 scatter path
        float* attNorm = (float*)d_ws;
        const int ldsBytes = 3 * LATD * WPAD * sizeof(_Float16);  // 104448 B
        hipMemsetAsync(out,     0, (size_t)NNODE * LATD  * sizeof(float), stream);
        hipMemsetAsync(attNorm, 0, (size_t)NNODE * NHEAD * sizeof(float), stream);
        hipFuncSetAttribute((const void*)edge_kernel,
                            hipFuncAttributeMaxDynamicSharedMemorySize, ldsBytes);
        edge_kernel<<<512, 512, ldsBytes, stream>>>(rows, colEmb, embeds, Qw, Kw, Vw, out, attNorm);
        const int nVec = NNODE * 32;
        norm_kernel<<<(nVec + 255) / 256, 256, 0, stream>>>(out, attNorm);
    }
}

// Round 17
// 414.213 us; speedup vs baseline: 1.5642x; 1.0109x over previous
//
#include <hip/hip_runtime.h>
#include <hip/hip_bf16.h>

#define NEDGE 800000
#define NNODE 100000
#define LATD  128
#define NHEAD 4
#define WPAD  136            // padded LDS row length (halves): 272B stride
#define TILES (NEDGE / 16)   // 50000 exact
#define QTILES (NNODE / 16)  // 6250 exact
#define NB ((NNODE + 1023) / 1024)  // 98 scan blocks

typedef _Float16 half8 __attribute__((ext_vector_type(8)));
typedef _Float16 half4t __attribute__((ext_vector_type(4)));
typedef float    f32x4 __attribute__((ext_vector_type(4)));

__device__ __forceinline__ half8 load_frag_f32(const float* __restrict__ p) {
    const f32x4 a = *reinterpret_cast<const f32x4*>(p);
    const f32x4 b = *reinterpret_cast<const f32x4*>(p + 4);
    half8 r;
    r[0] = (_Float16)a[0]; r[1] = (_Float16)a[1];
    r[2] = (_Float16)a[2]; r[3] = (_Float16)a[3];
    r[4] = (_Float16)b[0]; r[5] = (_Float16)b[1];
    r[6] = (_Float16)b[2]; r[7] = (_Float16)b[3];
    return r;
}

// ---------------- qAll = embeds @ Q, fp16, PERMUTED layout ----------------
// storage: qAll[n*128 + (col&15)*8 + (col>>4)]
__global__ __launch_bounds__(512, 2) void q_kernel(
    const float* __restrict__ embeds,
    const float* __restrict__ Qw,
    _Float16* __restrict__ qAll)
{
    extern __shared__ _Float16 lds[];
    _Float16* Qt = lds;  // Qt[c][d] = Q[d][c]
    const int t = threadIdx.x;
    for (int idx = t; idx < LATD * LATD; idx += 512) {
        const int d = idx >> 7, c = idx & 127;
        Qt[c * WPAD + d] = (_Float16)Qw[idx];
    }
    __syncthreads();

    const int lane = t & 63;
    const int c16  = lane & 15;
    const int g    = lane >> 4;
    const int wave = (blockIdx.x << 3) + (t >> 6);
    const int nw   = gridDim.x << 3;

    for (int tile = wave; tile < QTILES; tile += nw) {
        const int n0 = tile << 4;
        const float* xrow = embeds + (size_t)(n0 + c16) * LATD + g * 8;
        f32x4 accQ[8] = {};
        #pragma unroll
        for (int ks = 0; ks < 4; ++ks) {
            const half8 ax = load_frag_f32(xrow + ks * 32);
            const int ko = ks * 32 + g * 8;
            #pragma unroll
            for (int nt = 0; nt < 8; ++nt) {
                const half8 bq = *reinterpret_cast<const half8*>(Qt + (nt * 16 + c16) * WPAD + ko);
                accQ[nt] = __builtin_amdgcn_mfma_f32_16x16x32_f16(ax, bq, accQ[nt], 0, 0, 0);
            }
        }
        #pragma unroll
        for (int r = 0; r < 4; ++r) {
            half8 h;
            #pragma unroll
            for (int nt = 0; nt < 8; ++nt) h[nt] = (_Float16)accQ[nt][r];
            *reinterpret_cast<half8*>(qAll + (size_t)(n0 + g * 4 + r) * LATD + c16 * 8) = h;
        }
    }
}

// ---------------- CSR build ----------------
__global__ void hist_kernel(const int* __restrict__ rows, int* __restrict__ counts) {
    const int e = blockIdx.x * 256 + threadIdx.x;
    if (e < NEDGE) atomicAdd(&counts[rows[e]], 1);
}

__global__ __launch_bounds__(1024) void scan1_kernel(
    const int* __restrict__ counts, int* __restrict__ offsets, int* __restrict__ partials)
{
    __shared__ int wt[16];
    __shared__ int wp[16];
    const int b = blockIdx.x;
    const int i = b * 1024 + threadIdx.x;
    const int v = (i < NNODE) ? counts[i] : 0;
    const int lane = threadIdx.x & 63, wid = threadIdx.x >> 6;
    int incl = v;
    #pragma unroll
    for (int d = 1; d < 64; d <<= 1) {
        const int x = __shfl_up(incl, d);
        if (lane >= d) incl += x;
    }
    if (lane == 63) wt[wid] = incl;
    __syncthreads();
    if (threadIdx.x == 0) {
        int s = 0;
        for (int k = 0; k < 16; ++k) { wp[k] = s; s += wt[k]; }
        partials[b] = s;
    }
    __syncthreads();
    if (i < NNODE) offsets[i] = incl - v + wp[wid];
}

__global__ __launch_bounds__(1024) void scan2_kernel(
    int* __restrict__ offsets, int* __restrict__ cursor, const int* __restrict__ partials)
{
    __shared__ int sp[128];
    const int b = blockIdx.x;
    if (threadIdx.x < NB) sp[threadIdx.x] = partials[threadIdx.x];
    __syncthreads();
    int s = 0;
    for (int k = 0; k < b; ++k) s += sp[k];
    const int i = b * 1024 + threadIdx.x;
    if (i < NNODE) {
        const int val = offsets[i] + s;
        offsets[i] = val;
        cursor[i]  = val;
    }
    if (b == 0 && threadIdx.x == 0) offsets[NNODE] = NEDGE;
}

__global__ void scatter_kernel(const int* __restrict__ rows,
                               int* __restrict__ cursor,
                               int* __restrict__ edgeIdx,
                               int* __restrict__ rowsSorted) {
    const int e = blockIdx.x * 256 + threadIdx.x;
    if (e < NEDGE) {
        const int r = rows[e];
        const int p = atomicAdd(&cursor[r], 1);
        edgeIdx[p]    = e;
        rowsSorted[p] = r;
    }
}

// ------ phase 1: att_kernel (R12 shape). Natural-order streaming colEmb,
//        Kt-ONLY LDS (34.8 KB -> 2 blocks/CU = 16 waves), (512,2). ------
__global__ __launch_bounds__(512, 2) void att_kernel(
    const int*      __restrict__ rows,
    const float*    __restrict__ colEmb,
    const _Float16* __restrict__ qAll,
    const float*    __restrict__ Kw,
    _Float16* __restrict__ attN)
{
    extern __shared__ _Float16 lds[];
    _Float16* Kt = lds;                 // Kt[c][d] = K[d][c]
    const int t = threadIdx.x;
    for (int idx = t; idx < LATD * LATD; idx += 512) {
        const int d = idx >> 7, c = idx & 127;
        Kt[c * WPAD + d] = (_Float16)Kw[idx];
    }
    __syncthreads();

    const int lane = t & 63;
    const int c16  = lane & 15;
    const int g    = lane >> 4;
    const int wave = blockIdx.x * 8 + (t >> 6);
    const int nw   = gridDim.x * 8;

    for (int tile = wave; tile < TILES; tile += nw) {
        const int e0 = tile << 4;
        const float* yrow = colEmb + (size_t)(e0 + c16) * LATD + g * 8;  // streaming

        half8 ay[4];
        #pragma unroll
        for (int ks = 0; ks < 4; ++ks) ay[ks] = load_frag_f32(yrow + ks * 32);

        // q rows (gather from 25.6 MB L2/IC-resident qAll)
        const int4 rW = *reinterpret_cast<const int4*>(rows + e0 + g * 4);
        half8 qv[4];
        qv[0] = *reinterpret_cast<const half8*>(qAll + (size_t)rW.x * LATD + c16 * 8);
        qv[1] = *reinterpret_cast<const half8*>(qAll + (size_t)rW.y * LATD + c16 * 8);
        qv[2] = *reinterpret_cast<const half8*>(qAll + (size_t)rW.z * LATD + c16 * 8);
        qv[3] = *reinterpret_cast<const half8*>(qAll + (size_t)rW.w * LATD + c16 * 8);

        f32x4 accK[8] = {};
        #pragma unroll
        for (int ks = 0; ks < 4; ++ks) {
            const int ko = ks * 32 + g * 8;
            #pragma unroll
            for (int nt = 0; nt < 8; ++nt) {
                const half8 bk = *reinterpret_cast<const half8*>(Kt + (nt * 16 + c16) * WPAD + ko);
                accK[nt] = __builtin_amdgcn_mfma_f32_16x16x32_f16(ay[ks], bk, accK[nt], 0, 0, 0);
            }
        }

        // att = exp(clip(q.k)) per head; butterfly over the 16 c16 lanes
        f32x4 eh[4];
        #pragma unroll
        for (int h = 0; h < 4; ++h) {
            f32x4 p;
            #pragma unroll
            for (int r = 0; r < 4; ++r)
                p[r] = accK[2 * h][r]     * (float)qv[r][2 * h]
                     + accK[2 * h + 1][r] * (float)qv[r][2 * h + 1];
            #pragma unroll
            for (int m = 1; m < 16; m <<= 1) {
                f32x4 q;
                q[0] = __shfl_xor(p[0], m);
                q[1] = __shfl_xor(p[1], m);
                q[2] = __shfl_xor(p[2], m);
                q[3] = __shfl_xor(p[3], m);
                p += q;
            }
            #pragma unroll
            for (int r = 0; r < 4; ++r)
                eh[h][r] = expf(fminf(10.0f, fmaxf(-10.0f, p[r])));
        }

        // attN store: lanes c16<4 write head c16 for their 4 rows
        const f32x4 sel = (c16 == 0) ? eh[0] : (c16 == 1) ? eh[1] : (c16 == 2) ? eh[2] : eh[3];
        if (c16 < NHEAD) {
            #pragma unroll
            for (int r = 0; r < 4; ++r)
                attN[(size_t)(e0 + 4 * g + r) * NHEAD + c16] = (_Float16)sel[r];
        }
    }
}

// ------ phase 2: pv_kernel (512,2). MLP surgery: ay[4] upfront (4 outstanding
//        loads), a4 gathers issued BEFORE the MFMA loop, next-tile index prefetch. ------
__global__ __launch_bounds__(512, 2) void pv_kernel(
    const int*      __restrict__ edgeIdx,
    const int*      __restrict__ rowsSorted,
    const float*    __restrict__ colEmb,
    const _Float16* __restrict__ attN,
    const float*    __restrict__ Vw,
    float* __restrict__ outAcc,
    float* __restrict__ attNorm,
    int tilesPerWave)
{
    extern __shared__ _Float16 lds[];
    _Float16* Vt = lds;                 // Vt[c][d] = V[d][c]
    const int t = threadIdx.x;
    for (int idx = t; idx < LATD * LATD; idx += 512) {
        const int d = idx >> 7, c = idx & 127;
        Vt[c * WPAD + d] = (_Float16)Vw[idx];
    }
    __syncthreads();

    const int lane = t & 63;
    const int c16  = lane & 15;
    const int g    = lane >> 4;
    const int wave = blockIdx.x * 8 + (t >> 6);
    const int tile0 = wave * tilesPerWave;
    int tile1 = tile0 + tilesPerWave;
    if (tile1 > TILES) tile1 = TILES;
    if (tile0 >= tile1) return;

    // preload first tile's indices
    int eA      = edgeIdx[(tile0 << 4) + c16];
    int rid16   = rowsSorted[(tile0 << 4) + c16];
    int4 rB     = *reinterpret_cast<const int4*>(rowsSorted + (tile0 << 4) + g * 4);
    int4 eB     = *reinterpret_cast<const int4*>(edgeIdx    + (tile0 << 4) + g * 4);
    int prevRow = (g == 0) ? -1 : rowsSorted[(tile0 << 4) + 4 * g - 1];

    for (int tile = tile0; tile < tile1; ++tile) {
        // issue the colEmb gather for this tile immediately (4 outstanding 16B loads)
        const float* yrow = colEmb + (size_t)eA * LATD + g * 8;
        half8 ay[4];
        #pragma unroll
        for (int ks = 0; ks < 4; ++ks) ay[ks] = load_frag_f32(yrow + ks * 32);

        // attN gathers for this tile (independent of MFMA; hidden under it)
        half4t a4[4];
        a4[0] = *reinterpret_cast<const half4t*>(attN + (size_t)eB.x * NHEAD);
        a4[1] = *reinterpret_cast<const half4t*>(attN + (size_t)eB.y * NHEAD);
        a4[2] = *reinterpret_cast<const half4t*>(attN + (size_t)eB.z * NHEAD);
        a4[3] = *reinterpret_cast<const half4t*>(attN + (size_t)eB.w * NHEAD);

        // prefetch next tile's indices (hides index-load latency)
        const bool hasNext = (tile + 1 < tile1);
        int eAn = 0, rid16n = 0, prevRowN = 0;
        int4 rBn = rB, eBn = eB;
        if (hasNext) {
            const int i1 = (tile + 1) << 4;
            eAn     = edgeIdx[i1 + c16];
            rid16n  = rowsSorted[i1 + c16];
            rBn     = *reinterpret_cast<const int4*>(rowsSorted + i1 + g * 4);
            eBn     = *reinterpret_cast<const int4*>(edgeIdx    + i1 + g * 4);
            prevRowN = (g == 0) ? -1 : rowsSorted[i1 + 4 * g - 1];
        }

        // v matmul
        f32x4 accV[8] = {};
        #pragma unroll
        for (int ks = 0; ks < 4; ++ks) {
            const int ko = ks * 32 + g * 8;
            #pragma unroll
            for (int nt = 0; nt < 8; ++nt) {
                const half8 bv = *reinterpret_cast<const half8*>(Vt + (nt * 16 + c16) * WPAD + ko);
                accV[nt] = __builtin_amdgcn_mfma_f32_16x16x32_f16(ay[ks], bv, accV[nt], 0, 0, 0);
            }
        }

        // P-MFMA segment totals (k = 8g+r mapping, halves j>=4 zero);
        // D overwrites accV in place
        half8 Pf = {};
        Pf[0] = (rB.x == rid16) ? (_Float16)1.f : (_Float16)0.f;
        Pf[1] = (rB.y == rid16) ? (_Float16)1.f : (_Float16)0.f;
        Pf[2] = (rB.z == rid16) ? (_Float16)1.f : (_Float16)0.f;
        Pf[3] = (rB.w == rid16) ? (_Float16)1.f : (_Float16)0.f;

        const f32x4 zero4 = {};
        #pragma unroll
        for (int nt = 0; nt < 8; ++nt) {
            const int h = nt >> 1;
            half8 Wf = {};
            Wf[0] = (_Float16)(accV[nt][0] * (float)a4[0][h] * 0.015625f);
            Wf[1] = (_Float16)(accV[nt][1] * (float)a4[1][h] * 0.015625f);
            Wf[2] = (_Float16)(accV[nt][2] * (float)a4[2][h] * 0.015625f);
            Wf[3] = (_Float16)(accV[nt][3] * (float)a4[3][h] * 0.015625f);
            accV[nt] = __builtin_amdgcn_mfma_f32_16x16x32_f16(Pf, Wf, zero4, 0, 0, 0);
        }
        half8 Df = {};
        if (c16 < NHEAD) {
            Df[0] = a4[0][c16]; Df[1] = a4[1][c16];
            Df[2] = a4[2][c16]; Df[3] = a4[3][c16];
        }
        const f32x4 Dden = __builtin_amdgcn_mfma_f32_16x16x32_f16(Pf, Df, zero4, 0, 0, 0);

        // flush only at segment-head rows (accV holds D)
        #pragma unroll
        for (int r = 0; r < 4; ++r) {
            const int cur = (r == 0) ? rB.x : (r == 1) ? rB.y : (r == 2) ? rB.z : rB.w;
            const int prv = (r == 0) ? prevRow : (r == 1) ? rB.x : (r == 2) ? rB.y : rB.z;
            if (cur != prv) {
                #pragma unroll
                for (int nt = 0; nt < 8; ++nt)
                    atomicAdd(outAcc + (size_t)cur * LATD + nt * 16 + c16, accV[nt][r] * 64.0f);
                if (c16 < NHEAD) atomicAdd(attNorm + cur * NHEAD + c16, Dden[r]);
            }
        }

        // rotate prefetched indices
        if (hasNext) { eA = eAn; rid16 = rid16n; rB = rBn; eB = eBn; prevRow = prevRowN; }
    }
}

// out[n, j] /= (attNorm[n, j/32] + 1e-8)
__global__ void norm_kernel(float* __restrict__ out, const float* __restrict__ attNorm) {
    const int i = blockIdx.x * 256 + threadIdx.x;
    if (i >= NNODE * 32) return;
    const int n = i >> 5;
    const int h = (i & 31) >> 3;
    const float s = attNorm[n * NHEAD + h] + 1e-8f;
    f32x4* p = reinterpret_cast<f32x4*>(out) + i;
    f32x4 v = *p;
    v[0] /= s; v[1] /= s; v[2] /= s; v[3] /= s;
    *p = v;
}

// ================= fallback (round-1 scatter path, unsorted) =================
__global__ __launch_bounds__(512, 2) void edge_kernel(
    const int*   __restrict__ rows,
    const float* __restrict__ colEmb,
    const float* __restrict__ embeds,
    const float* __restrict__ Qw,
    const float* __restrict__ Kw,
    const float* __restrict__ Vw,
    float* __restrict__ outAcc,
    float* __restrict__ attNorm)
{
    extern __shared__ _Float16 lds[];
    _Float16* Qt = lds;
    _Float16* Kt = lds + LATD * WPAD;
    _Float16* Vt = lds + 2 * LATD * WPAD;
    const int t = threadIdx.x;
    for (int idx = t; idx < LATD * LATD; idx += 512) {
        const int d = idx >> 7, c = idx & 127;
        Qt[c * WPAD + d] = (_Float16)Qw[idx];
        Kt[c * WPAD + d] = (_Float16)Kw[idx];
        Vt[c * WPAD + d] = (_Float16)Vw[idx];
    }
    __syncthreads();
    const int lane = t & 63;
    const int c16  = lane & 15;
    const int g    = lane >> 4;
    const int wave = (blockIdx.x << 3) + (t >> 6);
    const int nw   = gridDim.x << 3;
    for (int tile = wave; tile < TILES; tile += nw) {
        const int e0 = tile << 4;
        const int eA = e0 + c16;
        const int rA = rows[eA];
        const float* xrow = embeds + (size_t)rA * LATD + g * 8;
        const float* yrow = colEmb + (size_t)eA * LATD + g * 8;
        half8 ay[4];
        f32x4 accQ[8] = {};
        f32x4 accK[8] = {};
        #pragma unroll
        for (int ks = 0; ks < 4; ++ks) {
            const int ko = ks * 32 + g * 8;
            const half8 ax = load_frag_f32(xrow + ks * 32);
            ay[ks] = load_frag_f32(yrow + ks * 32);
            #pragma unroll
            for (int nt = 0; nt < 8; ++nt) {
                const int rofs = (nt * 16 + c16) * WPAD + ko;
                const half8 bq = *reinterpret_cast<const half8*>(Qt + rofs);
                const half8 bk = *reinterpret_cast<const half8*>(Kt + rofs);
                accQ[nt] = __builtin_amdgcn_mfma_f32_16x16x32_f16(ax,     bq, accQ[nt], 0, 0, 0);
                accK[nt] = __builtin_amdgcn_mfma_f32_16x16x32_f16(ay[ks], bk, accK[nt], 0, 0, 0);
            }
        }
        f32x4 eh[4];
        #pragma unroll
        for (int h = 0; h < 4; ++h) {
            f32x4 p = accQ[2 * h] * accK[2 * h] + accQ[2 * h + 1] * accK[2 * h + 1];
            #pragma unroll
            for (int m = 1; m < 16; m <<= 1) {
                f32x4 q;
                q[0] = __shfl_xor(p[0], m);
                q[1] = __shfl_xor(p[1], m);
                q[2] = __shfl_xor(p[2], m);
                q[3] = __shfl_xor(p[3], m);
                p += q;
            }
            #pragma unroll
            for (int r = 0; r < 4; ++r)
                eh[h][r] = expf(fminf(10.0f, fmaxf(-10.0f, p[r])));
        }
        int rB[4];
        #pragma unroll
        for (int r = 0; r < 4; ++r) rB[r] = rows[e0 + g * 4 + r];
        if (c16 < NHEAD) {
            const f32x4 sel = (c16 == 0) ? eh[0] : (c16 == 1) ? eh[1] : (c16 == 2) ? eh[2] : eh[3];
            #pragma unroll
            for (int r = 0; r < 4; ++r)
                atomicAdd(attNorm + rB[r] * NHEAD + c16, sel[r]);
        }
        f32x4 accV[8] = {};
        #pragma unroll
        for (int ks = 0; ks < 4; ++ks) {
            const int ko = ks * 32 + g * 8;
            #pragma unroll
            for (int nt = 0; nt < 8; ++nt) {
                const half8 bv = *reinterpret_cast<const half8*>(Vt + (nt * 16 + c16) * WPAD + ko);
                accV[nt] = __builtin_amdgcn_mfma_f32_16x16x32_f16(ay[ks], bv, accV[nt], 0, 0, 0);
            }
        }
        #pragma unroll
        for (int nt = 0; nt < 8; ++nt) {
            const f32x4 w = accV[nt] * eh[nt >> 1];
            #pragma unroll
            for (int r = 0; r < 4; ++r)
                atomicAdd(outAcc + (size_t)rB[r] * LATD + nt * 16 + c16, w[r]);
        }
    }
}

extern "C" void kernel_launch(void* const* d_in, const int* in_sizes, int n_in,
                              void* d_out, int out_size, void* d_ws, size_t ws_size,
                              hipStream_t stream) {
    const int*   rows   = (const int*)d_in[0];
    const float* colEmb = (const float*)d_in[1];
    const float* embeds = (const float*)d_in[2];
    const float* Qw     = (const float*)d_in[3];
    const float* Kw     = (const float*)d_in[4];
    const float* Vw     = (const float*)d_in[5];
    float* out = (float*)d_out;

    // ws layout (256B-multiple chunks)
    const size_t qAllB = (size_t)NNODE * LATD * sizeof(_Float16);   // 25.6 MB
    const size_t cntB  = 400128;
    const size_t offB  = 402176;
    const size_t curB  = 400128;
    const size_t eidxB = (size_t)NEDGE * sizeof(int);               // 3.2 MB
    const size_t rsrtB = (size_t)NEDGE * sizeof(int);               // 3.2 MB
    const size_t partB = 512;
    const size_t attNB = (size_t)NEDGE * NHEAD * sizeof(_Float16);  // 6.4 MB
    const size_t attB  = (size_t)NNODE * NHEAD * sizeof(float);     // 1.6 MB
    const size_t needB = qAllB + cntB + offB + curB + eidxB + rsrtB + partB + attNB + attB;

    if (ws_size >= needB) {
        char* w = (char*)d_ws;
        _Float16* qAll    = (_Float16*)w; w += qAllB;
        int*   counts     = (int*)w;    w += cntB;
        int*   offsets    = (int*)w;    w += offB;
        int*   cursor     = (int*)w;    w += curB;
        int*   edgeIdx    = (int*)w;    w += eidxB;
        int*   rowsSorted = (int*)w;    w += rsrtB;
        int*   partials   = (int*)w;    w += partB;
        _Float16* attN    = (_Float16*)w; w += attNB;
        float* attNorm    = (float*)w;

        hipMemsetAsync(counts,  0, (size_t)NNODE * sizeof(int), stream);
        hipMemsetAsync(out,     0, (size_t)NNODE * LATD * sizeof(float), stream);
        hipMemsetAsync(attNorm, 0, (size_t)NNODE * NHEAD * sizeof(float), stream);

        const int ldsQ = LATD * WPAD * sizeof(_Float16);      // 34,816 B
        hipFuncSetAttribute((const void*)q_kernel,
                            hipFuncAttributeMaxDynamicSharedMemorySize, ldsQ);
        q_kernel<<<(QTILES + 7) / 8, 512, ldsQ, stream>>>(embeds, Qw, qAll);

        hist_kernel<<<(NEDGE + 255) / 256, 256, 0, stream>>>(rows, counts);
        scan1_kernel<<<NB, 1024, 0, stream>>>(counts, offsets, partials);
        scan2_kernel<<<NB, 1024, 0, stream>>>(offsets, cursor, partials);
        scatter_kernel<<<(NEDGE + 255) / 256, 256, 0, stream>>>(rows, cursor, edgeIdx, rowsSorted);

        // phase 1: att (Kt-only LDS, 16 waves/CU)
        hipFuncSetAttribute((const void*)att_kernel,
                            hipFuncAttributeMaxDynamicSharedMemorySize, ldsQ);
        att_kernel<<<1024, 512, ldsQ, stream>>>(rows, colEmb, qAll, Kw, attN);

        // phase 2: pv (Vt-only LDS, 16 waves/CU), chunked for atomic locality
        hipFuncSetAttribute((const void*)pv_kernel,
                            hipFuncAttributeMaxDynamicSharedMemorySize, ldsQ);
        const int nWaves = 1024 * 8;                       // 8192 waves
        const int tpw = (TILES + nWaves - 1) / nWaves;     // 7
        pv_kernel<<<1024, 512, ldsQ, stream>>>(
            edgeIdx, rowsSorted, colEmb, attN, Vw, out, attNorm, tpw);

        const int nVec = NNODE * 32;
        norm_kernel<<<(nVec + 255) / 256, 256, 0, stream>>>(out, attNorm);
    } else {
        // fallback: round-1 scatter path
        float* attNorm = (float*)d_ws;
        const int ldsBytes = 3 * LATD * WPAD * sizeof(_Float16);  // 104448 B
        hipMemsetAsync(out,     0, (size_t)NNODE * LATD  * sizeof(float), stream);
        hipMemsetAsync(attNorm, 0, (size_t)NNODE * NHEAD * sizeof(float), stream);
        hipFuncSetAttribute((const void*)edge_kernel,
                            hipFuncAttributeMaxDynamicSharedMemorySize, ldsBytes);
        edge_kernel<<<512, 512, ldsBytes, stream>>>(rows, colEmb, embeds, Qw, Kw, Vw, out, attNorm);
        const int nVec = NNODE * 32;
        norm_kernel<<<(nVec + 255) / 256, 256, 0, stream>>>(out, attNorm);
    }
}